// Round 13
// baseline (2831.573 us; speedup 1.0000x reference)
//
#include <hip/hip_runtime.h>

// ODEBlock1D RK4, B=32 L=8192 C=64. R13: BARRIER-FREE wave-private pipelines.
// Diagnosis: occupancy pinned at 3 waves/SIMD (regs ~144/wave) in every
// config; co-split waves force a block barrier per eval (A-frags need all 64
// channels). Fix: wave owns 40 rows x ALL 64 channels with private 48-row z
// dbuf (halo 4, fuse-1, shrinking-halo keeps stored rows [4,44) exact).
// Zero __syncthreads(). Bf doubles to [6][2][2] (96 regs); y re-read from
// global (L2-hot) per eval instead of yR regs. 2 indep waves/block,
// LDS 28.8KB -> 5 blocks/CU. 8 dispatches.

#define BB 32
#define LL 8192
#define CC 64
#define WTILE 40         // central rows stored per wave
#define WCROWS 48        // computed rows per wave (3 bands), r -> l = l0w-4+r
#define WBUFR 50         // + 2 conv-pad rows (z row = r+1)
#define ZST 72           // shorts per z row (144 B, 16B-aligned rows)
#define NBLK 103         // ceil(8192/80); block = 2 waves x 40 rows
#define THREADS 128

typedef __attribute__((ext_vector_type(8))) short bf16x8;
typedef __attribute__((ext_vector_type(4))) float f32x4;

__device__ __forceinline__ unsigned bf_rne(float f) {
    unsigned u = __float_as_uint(f);
    return u + 0x7fffu + ((u >> 16) & 1u);   // bf16 RNE in high 16 bits
}
__device__ __forceinline__ short bf16_of(float f) { return (short)(bf_rne(f) >> 16); }
__device__ __forceinline__ unsigned cvtpk(float lo, float hi) {
    unsigned r;
    asm("v_cvt_pk_bf16_f32 %0, %1, %2" : "=v"(r) : "v"(lo), "v"(hi));
    return r;
}

__launch_bounds__(THREADS, 2)
__global__ void step_kernel(const float* __restrict__ y_in, float* __restrict__ y_out,
                            const float* __restrict__ w, const float* __restrict__ bias,
                            float t0, float h)
{
    // per-wave private: [wave][dbuf][WBUFR*ZST]; 2*2*7200 B = 28800 B
    __shared__ unsigned short z[2][2][WBUFR * ZST];

    const int tid = threadIdx.x;
    const int b = blockIdx.y;
    const int lane = tid & 63;
    const int wv = tid >> 6;
    const int g = lane >> 4;
    const int ml = lane & 15;
    const int l0w = blockIdx.x * 80 + wv * WTILE;   // wave's first output row
    const bool edge = (l0w == 0) || (l0w >= LL - 44);

    // valid row range for this wave: r in [rminw, rmaxw) <-> l in [0, LL)
    const int rminw = (l0w == 0) ? 4 : 0;
    const int rmaxw = min(WCROWS, LL - l0w + 4);    // can be <= 0 for tail wave

    unsigned short* zA = &z[wv][0][0];
    unsigned short* zB = &z[wv][1][0];

    // zero conv-pad rows (z rows 0 and WBUFR-1) of both private buffers
    {
        unsigned* zp = (unsigned*)zA;               // both buffers contiguous
        if (lane < 36) {
            zp[lane] = 0;               zp[49 * 36 + lane] = 0;
            zp[1800 + lane] = 0;        zp[1800 + 49 * 36 + lane] = 0;
        }
    }

    // ---- B fragments, full 64 co per wave: Bf[c][n][p], co = n*32 + 2*ml + p
    bf16x8 Bf[6][2][2];
#pragma unroll
    for (int c = 0; c < 6; c++) {
        const float* wp = w + (c >> 1) * (65 * CC) + (((c & 1) * 32) + g * 8) * CC;
#pragma unroll
        for (int n = 0; n < 2; n++) {
            const float* wpn = wp + n * 32 + 2 * ml;
#pragma unroll
            for (int j = 0; j < 8; j++) {
                float2 v = *(const float2*)(wpn + j * CC);
                Bf[c][n][0][j] = bf16_of(v.x);
                Bf[c][n][1][j] = bf16_of(v.y);
            }
        }
    }
    float2 wt[3][2], bvn[2];
#pragma unroll
    for (int k = 0; k < 3; k++)
#pragma unroll
        for (int n = 0; n < 2; n++)
            wt[k][n] = *(const float2*)(w + k * (65 * CC) + CC * CC + n * 32 + 2 * ml);
#pragma unroll
    for (int n = 0; n < 2; n++)
        bvn[n] = *(const float2*)(bias + n * 32 + 2 * ml);

    // ---- stage wave-private z0 = bf16(y); 48 rows x 16 float4 / 64 lanes ----
    const float* yrow = y_in + ((size_t)b * LL + (size_t)(l0w - 4)) * CC;
#pragma unroll
    for (int it = 0; it < 12; it++) {
        const int idx = lane + it * 64;
        const int row = idx >> 4;
        const int c4 = (idx & 15) * 4;
        float4 v = make_float4(0.f, 0.f, 0.f, 0.f);
        if (row >= rminw && row < rmaxw)
            v = *(const float4*)(yrow + (size_t)row * CC + c4);
        uint2 p;
        p.x = cvtpk(v.x, v.y);
        p.y = cvtpk(v.z, v.w);
        *(uint2*)&zA[(row + 1) * ZST + c4] = p;
    }
    // no barrier: same-wave LDS ordering via lgkmcnt (compiler-inserted)

    float2 aR[3][2][4];

#pragma unroll 1
    for (int e = 0; e < 4; e++) {
        const unsigned short* zin = (e & 1) ? zB : zA;
        unsigned short* zout = (e & 1) ? zA : zB;
        const float cacc = (e == 1 || e == 2) ? (h / 3.f) : (h / 6.f);
        const float cuu  = (e == 2) ? h : (0.5f * h);
        const float tadd = (e == 3) ? h : ((e == 0) ? 0.f : (0.5f * h));
        const float t = t0 + tadd;
        float2 tb[2];
#pragma unroll
        for (int n = 0; n < 2; n++) {
            tb[n].x = t * (wt[0][n].x + wt[1][n].x + wt[2][n].x) + bvn[n].x;
            tb[n].y = t * (wt[0][n].y + wt[1][n].y + wt[2][n].y) + bvn[n].y;
        }

#pragma unroll
        for (int bb = 0; bb < 3; bb++) {
            const int r0 = bb * 16;
            f32x4 acc00 = {0.f, 0.f, 0.f, 0.f};
            f32x4 acc01 = {0.f, 0.f, 0.f, 0.f};
            f32x4 acc10 = {0.f, 0.f, 0.f, 0.f};
            f32x4 acc11 = {0.f, 0.f, 0.f, 0.f};
#pragma unroll
            for (int c = 0; c < 6; c++) {
                const int zr = r0 + ml + (c >> 1);
                const bf16x8 a =
                    *(const bf16x8*)&zin[zr * ZST + ((c & 1) * 32) + g * 8];
                acc00 = __builtin_amdgcn_mfma_f32_16x16x32_bf16(a, Bf[c][0][0], acc00, 0, 0, 0);
                acc01 = __builtin_amdgcn_mfma_f32_16x16x32_bf16(a, Bf[c][0][1], acc01, 0, 0, 0);
                acc10 = __builtin_amdgcn_mfma_f32_16x16x32_bf16(a, Bf[c][1][0], acc10, 0, 0, 0);
                acc11 = __builtin_amdgcn_mfma_f32_16x16x32_bf16(a, Bf[c][1][1], acc11, 0, 0, 0);
            }
#pragma unroll
            for (int i = 0; i < 4; i++) {
                const int r = r0 + g * 4 + i;
                const bool valid = (r >= rminw && r < rmaxw);
                const int l = l0w - 4 + r;
#pragma unroll
                for (int n = 0; n < 2; n++) {
                    float k0 = (n ? acc10[i] : acc00[i]) + tb[n].x;
                    float k1 = (n ? acc11[i] : acc01[i]) + tb[n].y;
                    if (edge) {
                        if (l == 0)      { k0 -= t * wt[0][n].x; k1 -= t * wt[0][n].y; }
                        if (l == LL - 1) { k0 -= t * wt[2][n].x; k1 -= t * wt[2][n].y; }
                    }
                    k0 = fmaxf(k0, 0.f);
                    k1 = fmaxf(k1, 0.f);
                    float2 y2 = make_float2(0.f, 0.f);
                    if (valid)
                        y2 = *(const float2*)(y_in + ((size_t)b * LL + l) * CC + n * 32 + 2 * ml);
                    if (e == 0) {
                        aR[bb][n][i].x = y2.x + cacc * k0;
                        aR[bb][n][i].y = y2.y + cacc * k1;
                    } else {
                        aR[bb][n][i].x += cacc * k0;
                        aR[bb][n][i].y += cacc * k1;
                    }
                    if (e < 3) {
                        float u0 = 0.f, u1 = 0.f;
                        if (valid) {
                            u0 = y2.x + cuu * k0;
                            u1 = y2.y + cuu * k1;
                        }
                        *(unsigned*)&zout[(r + 1) * ZST + n * 32 + 2 * ml] = cvtpk(u0, u1);
                    }
                }
            }
        }
        // no barrier: wave-private buffers, lgkmcnt ordering only
    }

    // ---- store central rows r in [4, 4+WTILE) and < rmaxw ----
#pragma unroll
    for (int bb = 0; bb < 3; bb++) {
#pragma unroll
        for (int i = 0; i < 4; i++) {
            const int r = bb * 16 + g * 4 + i;
            if (r >= 4 && r < 4 + WTILE && r < rmaxw) {
                const int l = l0w - 4 + r;
#pragma unroll
                for (int n = 0; n < 2; n++)
                    *(float2*)(y_out + ((size_t)b * LL + l) * CC + n * 32 + 2 * ml) = aR[bb][n][i];
            }
        }
    }
}

extern "C" void kernel_launch(void* const* d_in, const int* in_sizes, int n_in,
                              void* d_out, int out_size, void* d_ws, size_t ws_size,
                              hipStream_t stream) {
    const float* x = (const float*)d_in[0];
    const float* w = (const float*)d_in[1];
    const float* bias = (const float*)d_in[2];
    float* out = (float*)d_out;
    float* P0 = (float*)d_ws;   // 32*8192*64*4 = 67.1 MB scratch
    const float h = 1.0f / 8.0f;

    dim3 grid(NBLK, BB), block(THREADS);
    for (int s = 0; s < 8; s++) {
        const float* yin = (s == 0) ? x : ((s & 1) ? P0 : out);
        float* yout = (s & 1) ? out : P0;   // step 7 (s=7, odd) writes `out`
        step_kernel<<<grid, block, 0, stream>>>(yin, yout, w, bias, s * h, h);
    }
}

// Round 14
// 675.692 us; speedup vs baseline: 4.1906x; 4.1906x over previous
//
#include <hip/hip_runtime.h>

// ODEBlock1D RK4, B=32 L=8192 C=64. R14: R12 (best, 674.8us) + s_setprio
// around each band's 6-MFMA dependency chain (T5). Regime matches m191
// (independent de-phased blocks per CU, +4-7%), not m190's lockstep null:
// 3 block-pipelines/CU alternate MFMA-burst / VALU-epilogue / barrier, so
// priority lets MFMA-phase waves issue past other blocks' epilogue VALU.
// Everything else identical to R12 (fuse-2, yR-in-regs, cvt_pk, coeff
// selects, (256,3)). R13's barrier-free design died on the register wall
// (needs ~200 regs/wave; spilled at 128 -> 2832us).

#define BB 32
#define LL 8192
#define CC 64
#define HALO 8           // 8 evals x 1 conv-halo row per eval, each side
#define TILE 80          // central rows stored per block (CROWS - 2*HALO)
#define NBLK 103         // ceil(8192/80)
#define CROWS 96         // compute rows (6 MFMA bands), r -> l = l0-HALO+r
#define BUFR 98          // + 2 conv-pad rows (z row = r+1)
#define ZST 72           // shorts per z row (144 B, 16B-aligned rows)
#define THREADS 256

typedef __attribute__((ext_vector_type(8))) short bf16x8;
typedef __attribute__((ext_vector_type(4))) float f32x4;

__device__ __forceinline__ unsigned bf_rne(float f) {
    unsigned u = __float_as_uint(f);
    return u + 0x7fffu + ((u >> 16) & 1u);   // bf16 RNE in high 16 bits
}
__device__ __forceinline__ short bf16_of(float f) { return (short)(bf_rne(f) >> 16); }
__device__ __forceinline__ unsigned cvtpk(float lo, float hi) {
    // low16 = bf16_rne(lo), high16 = bf16_rne(hi) in one VALU op
    unsigned r;
    asm("v_cvt_pk_bf16_f32 %0, %1, %2" : "=v"(r) : "v"(lo), "v"(hi));
    return r;
}

__launch_bounds__(THREADS, 3)
__global__ void step_kernel(const float* __restrict__ y_in, float* __restrict__ y_out,
                            const float* __restrict__ w, const float* __restrict__ bias,
                            float t0, float h)
{
    __shared__ unsigned short zA[BUFR * ZST];   // 14112 B
    __shared__ unsigned short zB[BUFR * ZST];   // 14112 B  (total 28224 B)

    const int tid = threadIdx.x;
    const int b = blockIdx.y;
    const int l0 = blockIdx.x * TILE;
    const int lane = tid & 63;
    const int wv = tid >> 6;
    const int ch = wv & 1;             // co half: co in [ch*32, ch*32+32)
    const int rh = wv >> 1;            // row half: bands rh*3 .. rh*3+2
    const int g = lane >> 4;
    const int ml = lane & 15;
    const int co = ch * 32 + 2 * ml;   // lane's adjacent co pair
    const bool edge = (blockIdx.x == 0) || (blockIdx.x == NBLK - 1);

    // valid row range: r in [rmin, rmax) <-> l in [0, LL)
    const int rmin = (blockIdx.x == 0) ? HALO : 0;
    const int rmax = min(CROWS, LL - l0 + HALO);

    // zero conv-pad rows (z rows 0 and BUFR-1) of both buffers
    if (tid < 64) {
        zA[tid] = 0; zA[(BUFR - 1) * ZST + tid] = 0;
        zB[tid] = 0; zB[(BUFR - 1) * ZST + tid] = 0;
    }

    // ---- B fragments (bf16 RNE): chunk c: kw=c>>1, ci=(c&1)*32 + g*8 + j ----
    bf16x8 Bf[6][2];
#pragma unroll
    for (int c = 0; c < 6; c++) {
        const float* wp = w + (c >> 1) * (65 * CC) + (((c & 1) * 32) + g * 8) * CC + co;
#pragma unroll
        for (int j = 0; j < 8; j++) {
            float2 v = *(const float2*)(wp + j * CC);
            Bf[c][0][j] = bf16_of(v.x);
            Bf[c][1][j] = bf16_of(v.y);
        }
    }
    const float2 wt0 = *(const float2*)(w + 0 * (65 * CC) + CC * CC + co);
    const float2 wt1 = *(const float2*)(w + 1 * (65 * CC) + CC * CC + co);
    const float2 wt2 = *(const float2*)(w + 2 * (65 * CC) + CC * CC + co);
    const float2 bv  = *(const float2*)(bias + co);

    // ---- stage: z0 = bf16(y) -> zA; coalesced float4 ----
    const float* yrow = y_in + ((size_t)b * LL + (size_t)(l0 - HALO)) * CC;
    for (int idx = tid; idx < CROWS * 16; idx += THREADS) {
        const int row = idx >> 4;
        const int c4 = (idx & 15) * 4;
        float4 v = make_float4(0.f, 0.f, 0.f, 0.f);
        if (row >= rmin && row < rmax)
            v = *(const float4*)(yrow + (size_t)row * CC + c4);
        uint2 p;
        p.x = cvtpk(v.x, v.y);
        p.y = cvtpk(v.z, v.w);
        *(uint2*)&zA[(row + 1) * ZST + c4] = p;
    }

    // ---- y base into registers at this lane's output positions (fp32) ----
    float2 yR[3][4];
#pragma unroll
    for (int bb = 0; bb < 3; bb++) {
#pragma unroll
        for (int i = 0; i < 4; i++) {
            const int r = (rh * 3 + bb) * 16 + g * 4 + i;
            float2 v = make_float2(0.f, 0.f);
            if (r >= rmin && r < rmax)
                v = *(const float2*)(y_in + ((size_t)b * LL + (size_t)(l0 - HALO + r)) * CC + co);
            yR[bb][i] = v;
        }
    }
    __syncthreads();

    float2 aR[3][4];

#pragma unroll 1
    for (int e4 = 0; e4 < 8; e4++) {
        const int e = e4 & 3;
        const unsigned short* zin = (e4 & 1) ? zB : zA;
        unsigned short* zout = (e4 & 1) ? zA : zB;
        // RK4 coefficients via wave-uniform selects (no runtime-indexed arrays)
        const float cacc = (e == 1 || e == 2) ? (h / 3.f) : (h / 6.f);
        const float cuu  = (e == 2) ? h : (0.5f * h);        // e==3: unused
        const float tadd = (e == 3) ? h : ((e == 0) ? 0.f : (0.5f * h));
        const float t = t0 + ((e4 >> 2) ? h : 0.f) + tadd;
        const float tbx = t * (wt0.x + wt1.x + wt2.x) + bv.x;
        const float tby = t * (wt0.y + wt1.y + wt2.y) + bv.y;

#pragma unroll
        for (int bb = 0; bb < 3; bb++) {
            const int r0 = (rh * 3 + bb) * 16;
            f32x4 acc0 = {0.f, 0.f, 0.f, 0.f};
            f32x4 acc1 = {0.f, 0.f, 0.f, 0.f};
            __builtin_amdgcn_s_setprio(1);   // favor MFMA-phase wave on CU
#pragma unroll
            for (int c = 0; c < 6; c++) {
                const int zr = r0 + ml + (c >> 1);   // data row r0+ml-1+kw -> z row +1
                const bf16x8 a =
                    *(const bf16x8*)&zin[zr * ZST + ((c & 1) * 32) + g * 8];
                acc0 = __builtin_amdgcn_mfma_f32_16x16x32_bf16(a, Bf[c][0], acc0, 0, 0, 0);
                acc1 = __builtin_amdgcn_mfma_f32_16x16x32_bf16(a, Bf[c][1], acc1, 0, 0, 0);
            }
            __builtin_amdgcn_s_setprio(0);   // back to normal for epilogue
#pragma unroll
            for (int i = 0; i < 4; i++) {
                const int r = r0 + g * 4 + i;
                float k0 = acc0[i] + tbx;
                float k1 = acc1[i] + tby;
                if (edge) {
                    const int l = l0 - HALO + r;
                    if (l == 0)      { k0 -= t * wt0.x; k1 -= t * wt0.y; }
                    if (l == LL - 1) { k0 -= t * wt2.x; k1 -= t * wt2.y; }
                }
                k0 = fmaxf(k0, 0.f);
                k1 = fmaxf(k1, 0.f);
                const float2 y2 = yR[bb][i];
                if (e == 0) {
                    aR[bb][i].x = y2.x + cacc * k0;
                    aR[bb][i].y = y2.y + cacc * k1;
                } else {
                    aR[bb][i].x += cacc * k0;
                    aR[bb][i].y += cacc * k1;
                }
                if (e4 == 3)   // step-1 done: new y base = aR, stays in regs
                    yR[bb][i] = aR[bb][i];
                if (e4 != 7) {
                    float u0 = 0.f, u1 = 0.f;
                    if (r >= rmin && r < rmax) {     // seq-boundary rows stay 0
                        if (e == 3) { u0 = yR[bb][i].x; u1 = yR[bb][i].y; }
                        else        { u0 = y2.x + cuu * k0; u1 = y2.y + cuu * k1; }
                    }
                    *(unsigned*)&zout[(r + 1) * ZST + co] = cvtpk(u0, u1);
                }
            }
        }
        if (e4 != 7) __syncthreads();
    }

    // ---- store central rows (r in [HALO, HALO+TILE) and < rmax) ----
#pragma unroll
    for (int bb = 0; bb < 3; bb++) {
        const int r0 = (rh * 3 + bb) * 16;
#pragma unroll
        for (int i = 0; i < 4; i++) {
            const int r = r0 + g * 4 + i;
            if (r >= HALO && r < HALO + TILE && r < rmax) {
                const int l = l0 - HALO + r;
                *(float2*)(y_out + ((size_t)b * LL + l) * CC + co) = aR[bb][i];
            }
        }
    }
}

extern "C" void kernel_launch(void* const* d_in, const int* in_sizes, int n_in,
                              void* d_out, int out_size, void* d_ws, size_t ws_size,
                              hipStream_t stream) {
    const float* x = (const float*)d_in[0];
    const float* w = (const float*)d_in[1];
    const float* bias = (const float*)d_in[2];
    float* out = (float*)d_out;
    float* P0 = (float*)d_ws;   // 32*8192*64*4 = 67.1 MB scratch
    const float h = 1.0f / 8.0f;

    dim3 grid(NBLK, BB), block(THREADS);
    for (int s = 0; s < 4; s++) {   // each kernel = 2 fused RK4 steps
        const float* yin = (s == 0) ? x : ((s & 1) ? P0 : out);
        float* yout = (s & 1) ? out : P0;   // s=3 (odd) writes `out`
        step_kernel<<<grid, block, 0, stream>>>(yin, yout, w, bias, (2 * s) * h, h);
    }
}